// Round 1
// baseline (1098.535 us; speedup 1.0000x reference)
//
#include <hip/hip_runtime.h>
#include <hip/hip_bf16.h>

#define cN0 500000
#define cN1 100000
#define cN2 25000
#define cE0 1600000
#define cE1 400000

// ---------------- CSR build ----------------

__global__ void k_hist(const int* __restrict__ dst, int E, int* __restrict__ cnt) {
    int i = blockIdx.x * blockDim.x + threadIdx.x;
    if (i < E) atomicAdd(&cnt[dst[i]], 1);
}

// exclusive scan, 1024 elems/block (256 thr x 4), in-place; block sums out
__global__ void k_scan1(int* __restrict__ a, int n, int* __restrict__ bsum) {
    __shared__ int lds[256];
    const int t = threadIdx.x;
    const int base = blockIdx.x * 1024 + t * 4;
    int v0 = (base + 0 < n) ? a[base + 0] : 0;
    int v1 = (base + 1 < n) ? a[base + 1] : 0;
    int v2 = (base + 2 < n) ? a[base + 2] : 0;
    int v3 = (base + 3 < n) ? a[base + 3] : 0;
    const int s = v0 + v1 + v2 + v3;
    lds[t] = s;
    __syncthreads();
    int x = s;
    for (int d = 1; d < 256; d <<= 1) {
        int y = (t >= d) ? lds[t - d] : 0;
        __syncthreads();
        x += y;
        lds[t] = x;
        __syncthreads();
    }
    if (t == 255) bsum[blockIdx.x] = x;
    int e0 = x - s;           // exclusive prefix of this thread's chunk
    int e1 = e0 + v0, e2 = e1 + v1, e3 = e2 + v2;
    if (base + 0 < n) a[base + 0] = e0;
    if (base + 1 < n) a[base + 1] = e1;
    if (base + 2 < n) a[base + 2] = e2;
    if (base + 3 < n) a[base + 3] = e3;
}

// exclusive scan of <=128 block sums, single block of 128 threads
__global__ void k_scan2(int* __restrict__ bsum, int nb) {
    __shared__ int lds[128];
    const int t = threadIdx.x;
    int v = (t < nb) ? bsum[t] : 0;
    lds[t] = v;
    __syncthreads();
    int x = v;
    for (int d = 1; d < 128; d <<= 1) {
        int y = (t >= d) ? lds[t - d] : 0;
        __syncthreads();
        x += y;
        lds[t] = x;
        __syncthreads();
    }
    if (t < nb) bsum[t] = x - v;
}

__global__ void k_scan3(int* __restrict__ a, int n, const int* __restrict__ bsum, int total) {
    int i = blockIdx.x * blockDim.x + threadIdx.x;
    if (i < n) a[i] += bsum[i >> 10];
    if (i == 0) a[n] = total;
}

__global__ void k_copy(int* __restrict__ dst, const int* __restrict__ src, int n) {
    int i = blockIdx.x * blockDim.x + threadIdx.x;
    if (i < n) dst[i] = src[i];
}

__global__ void k_scatter(const int* __restrict__ esrc, const int* __restrict__ edst, int E,
                          int* __restrict__ cur, int* __restrict__ srcs) {
    int i = blockIdx.x * blockDim.x + threadIdx.x;
    if (i < E) {
        int p = atomicAdd(&cur[edst[i]], 1);
        srcs[p] = esrc[i];
    }
}

// out[c][r] = in[r][c];  in is [R][C]
__global__ void k_transpose(const float* __restrict__ in, float* __restrict__ out, int R, int C) {
    int i = blockIdx.x * blockDim.x + threadIdx.x;
    if (i < R * C) {
        int r = i / C, c = i - r * C;
        out[c * R + r] = in[i];
    }
}

// ---------------- hop 0: aggregate(x, E0) -> [32x128] tiles; h = relu(A*Wl^T + b + X*Wr^T) ----------------
// block = 256 thr, 32 dst nodes/block. Wlt/Wrt are transposed: [128][256].
__global__ __launch_bounds__(256) void k_hop0(
    const float* __restrict__ x,
    const int* __restrict__ off, const int* __restrict__ srcs,
    const float* __restrict__ Wlt, const float* __restrict__ Wrt,
    const float* __restrict__ bias,
    float* __restrict__ h)
{
    __shared__ float A[32][128];
    __shared__ float X[32][128];
    const int tid = threadIdx.x;
    const int wave = tid >> 6, lane = tid & 63;
    const int base = blockIdx.x * 32;

    // Phase A: mean-aggregate + load root rows (wave handles 8 nodes, lane = 2 dims)
    for (int i = 0; i < 8; ++i) {
        const int m = wave * 8 + i;
        const int g = base + m;
        float ax = 0.f, ay = 0.f, xx = 0.f, xy = 0.f;
        if (g < cN1) {
            const int e0 = off[g], e1 = off[g + 1];
            int e = e0;
            for (; e + 4 <= e1; e += 4) {
                const int s0 = srcs[e], s1 = srcs[e + 1], s2 = srcs[e + 2], s3 = srcs[e + 3];
                const float2 r0 = *(const float2*)(x + (size_t)s0 * 128 + lane * 2);
                const float2 r1 = *(const float2*)(x + (size_t)s1 * 128 + lane * 2);
                const float2 r2 = *(const float2*)(x + (size_t)s2 * 128 + lane * 2);
                const float2 r3 = *(const float2*)(x + (size_t)s3 * 128 + lane * 2);
                ax += (r0.x + r1.x) + (r2.x + r3.x);
                ay += (r0.y + r1.y) + (r2.y + r3.y);
            }
            for (; e < e1; ++e) {
                const int s = srcs[e];
                const float2 r = *(const float2*)(x + (size_t)s * 128 + lane * 2);
                ax += r.x; ay += r.y;
            }
            const int cnt = e1 - e0;
            const float inv = 1.f / (float)(cnt > 0 ? cnt : 1);
            ax *= inv; ay *= inv;
            const float2 xd = *(const float2*)(x + (size_t)g * 128 + lane * 2);
            xx = xd.x; xy = xd.y;
        }
        A[m][lane * 2] = ax; A[m][lane * 2 + 1] = ay;
        X[m][lane * 2] = xx; X[m][lane * 2 + 1] = xy;
    }
    __syncthreads();

    // Phase B: thread = 8 rows x 4 cols of the [32 x 256] output tile
    const int rg = tid >> 6;           // rows rg*8 .. rg*8+7
    const int j0 = (tid & 63) * 4;     // cols j0..j0+3
    float c[8][4];
    {
        const float b0 = bias[j0], b1 = bias[j0 + 1], b2 = bias[j0 + 2], b3 = bias[j0 + 3];
        #pragma unroll
        for (int r = 0; r < 8; ++r) { c[r][0] = b0; c[r][1] = b1; c[r][2] = b2; c[r][3] = b3; }
    }
    #pragma unroll 2
    for (int k = 0; k < 128; ++k) {
        const float4 wl = *(const float4*)(Wlt + k * 256 + j0);
        const float4 wr = *(const float4*)(Wrt + k * 256 + j0);
        #pragma unroll
        for (int r = 0; r < 8; ++r) {
            const float a = A[rg * 8 + r][k];
            const float xv = X[rg * 8 + r][k];
            c[r][0] += a * wl.x + xv * wr.x;
            c[r][1] += a * wl.y + xv * wr.y;
            c[r][2] += a * wl.z + xv * wr.z;
            c[r][3] += a * wl.w + xv * wr.w;
        }
    }
    #pragma unroll
    for (int r = 0; r < 8; ++r) {
        const int g = base + rg * 8 + r;
        if (g < cN1) {
            float4 v;
            v.x = fmaxf(c[r][0], 0.f); v.y = fmaxf(c[r][1], 0.f);
            v.z = fmaxf(c[r][2], 0.f); v.w = fmaxf(c[r][3], 0.f);
            *(float4*)(h + (size_t)g * 256 + j0) = v;
        }
    }
}

// ---------------- hop 1: aggregate(h, E1); out = A*Wl1^T + b + X*Wr1^T (no relu) ----------------
// block = 256 thr, 32 dst nodes/block. Wlt/Wrt transposed: [256][128].
__global__ __launch_bounds__(256) void k_hop1(
    const float* __restrict__ h,
    const int* __restrict__ off, const int* __restrict__ srcs,
    const float* __restrict__ Wlt, const float* __restrict__ Wrt,
    const float* __restrict__ bias,
    float* __restrict__ out)
{
    __shared__ float A[32][256];
    __shared__ float X[32][256];
    const int tid = threadIdx.x;
    const int wave = tid >> 6, lane = tid & 63;
    const int base = blockIdx.x * 32;

    for (int i = 0; i < 8; ++i) {
        const int m = wave * 8 + i;
        const int g = base + m;
        float4 acc = {0.f, 0.f, 0.f, 0.f};
        float4 xd  = {0.f, 0.f, 0.f, 0.f};
        if (g < cN2) {
            const int e0 = off[g], e1 = off[g + 1];
            int e = e0;
            for (; e + 4 <= e1; e += 4) {
                const int s0 = srcs[e], s1 = srcs[e + 1], s2 = srcs[e + 2], s3 = srcs[e + 3];
                const float4 r0 = *(const float4*)(h + (size_t)s0 * 256 + lane * 4);
                const float4 r1 = *(const float4*)(h + (size_t)s1 * 256 + lane * 4);
                const float4 r2 = *(const float4*)(h + (size_t)s2 * 256 + lane * 4);
                const float4 r3 = *(const float4*)(h + (size_t)s3 * 256 + lane * 4);
                acc.x += (r0.x + r1.x) + (r2.x + r3.x);
                acc.y += (r0.y + r1.y) + (r2.y + r3.y);
                acc.z += (r0.z + r1.z) + (r2.z + r3.z);
                acc.w += (r0.w + r1.w) + (r2.w + r3.w);
            }
            for (; e < e1; ++e) {
                const int s = srcs[e];
                const float4 r = *(const float4*)(h + (size_t)s * 256 + lane * 4);
                acc.x += r.x; acc.y += r.y; acc.z += r.z; acc.w += r.w;
            }
            const int cnt = e1 - e0;
            const float inv = 1.f / (float)(cnt > 0 ? cnt : 1);
            acc.x *= inv; acc.y *= inv; acc.z *= inv; acc.w *= inv;
            xd = *(const float4*)(h + (size_t)g * 256 + lane * 4);
        }
        *(float4*)&A[m][lane * 4] = acc;
        *(float4*)&X[m][lane * 4] = xd;
    }
    __syncthreads();

    // Phase B: thread = 4 rows x 4 cols of the [32 x 128] output tile
    const int rg = tid >> 5;           // 0..7 -> rows rg*4..rg*4+3
    const int j0 = (tid & 31) * 4;     // cols j0..j0+3
    float c[4][4];
    {
        const float b0 = bias[j0], b1 = bias[j0 + 1], b2 = bias[j0 + 2], b3 = bias[j0 + 3];
        #pragma unroll
        for (int r = 0; r < 4; ++r) { c[r][0] = b0; c[r][1] = b1; c[r][2] = b2; c[r][3] = b3; }
    }
    #pragma unroll 2
    for (int k = 0; k < 256; ++k) {
        const float4 wl = *(const float4*)(Wlt + k * 128 + j0);
        const float4 wr = *(const float4*)(Wrt + k * 128 + j0);
        #pragma unroll
        for (int r = 0; r < 4; ++r) {
            const float a = A[rg * 4 + r][k];
            const float xv = X[rg * 4 + r][k];
            c[r][0] += a * wl.x + xv * wr.x;
            c[r][1] += a * wl.y + xv * wr.y;
            c[r][2] += a * wl.z + xv * wr.z;
            c[r][3] += a * wl.w + xv * wr.w;
        }
    }
    #pragma unroll
    for (int r = 0; r < 4; ++r) {
        const int g = base + rg * 4 + r;
        if (g < cN2) {
            float4 v; v.x = c[r][0]; v.y = c[r][1]; v.z = c[r][2]; v.w = c[r][3];
            *(float4*)(out + (size_t)g * 128 + j0) = v;
        }
    }
}

// ---------------- launch ----------------

extern "C" void kernel_launch(void* const* d_in, const int* in_sizes, int n_in,
                              void* d_out, int out_size, void* d_ws, size_t ws_size,
                              hipStream_t stream) {
    const float* x   = (const float*)d_in[0];
    const float* Wl0 = (const float*)d_in[1];
    const float* bl0 = (const float*)d_in[2];
    const float* Wr0 = (const float*)d_in[3];
    const float* Wl1 = (const float*)d_in[4];
    const float* bl1 = (const float*)d_in[5];
    const float* Wr1 = (const float*)d_in[6];
    const int* e0s = (const int*)d_in[7];
    const int* e0d = (const int*)d_in[8];
    const int* e1s = (const int*)d_in[9];
    const int* e1d = (const int*)d_in[10];
    float* out = (float*)d_out;

    char* ws = (char*)d_ws;
    size_t pos = 0;
    auto alloc = [&](size_t nb) -> void* {
        void* p = ws + pos;
        pos += (nb + 255) & ~(size_t)255;
        return p;
    };
    float* h    = (float*)alloc((size_t)cN1 * 256 * 4);   // 102.4 MB
    int* off0   = (int*)alloc((size_t)(cN1 + 1) * 4);
    int* cur0   = (int*)alloc((size_t)cN1 * 4);
    int* srcs0  = (int*)alloc((size_t)cE0 * 4);
    int* off1   = (int*)alloc((size_t)(cN2 + 1) * 4);
    int* cur1   = (int*)alloc((size_t)cN2 * 4);
    int* srcs1  = (int*)alloc((size_t)cE1 * 4);
    int* bsum   = (int*)alloc(128 * 4);
    float* Wlt0 = (float*)alloc(128 * 256 * 4);
    float* Wrt0 = (float*)alloc(128 * 256 * 4);
    float* Wlt1 = (float*)alloc(256 * 128 * 4);
    float* Wrt1 = (float*)alloc(256 * 128 * 4);
    (void)ws_size; (void)in_sizes; (void)n_in; (void)out_size;

    // --- CSR hop0 ---
    hipMemsetAsync(off0, 0, (size_t)(cN1 + 1) * 4, stream);
    hipMemsetAsync(off1, 0, (size_t)(cN2 + 1) * 4, stream);
    k_hist<<<(cE0 + 255) / 256, 256, 0, stream>>>(e0d, cE0, off0);
    k_hist<<<(cE1 + 255) / 256, 256, 0, stream>>>(e1d, cE1, off1);

    const int nb0 = (cN1 + 1023) / 1024;   // 98
    k_scan1<<<nb0, 256, 0, stream>>>(off0, cN1, bsum);
    k_scan2<<<1, 128, 0, stream>>>(bsum, nb0);
    k_scan3<<<(cN1 + 255) / 256, 256, 0, stream>>>(off0, cN1, bsum, cE0);
    k_copy<<<(cN1 + 255) / 256, 256, 0, stream>>>(cur0, off0, cN1);
    k_scatter<<<(cE0 + 255) / 256, 256, 0, stream>>>(e0s, e0d, cE0, cur0, srcs0);

    // --- CSR hop1 (bsum reused after hop0 scan done; stream-ordered) ---
    const int nb1 = (cN2 + 1023) / 1024;   // 25
    k_scan1<<<nb1, 256, 0, stream>>>(off1, cN2, bsum);
    k_scan2<<<1, 128, 0, stream>>>(bsum, nb1);
    k_scan3<<<(cN2 + 255) / 256, 256, 0, stream>>>(off1, cN2, bsum, cE1);
    k_copy<<<(cN2 + 255) / 256, 256, 0, stream>>>(cur1, off1, cN2);
    k_scatter<<<(cE1 + 255) / 256, 256, 0, stream>>>(e1s, e1d, cE1, cur1, srcs1);

    // --- weight transposes ---
    k_transpose<<<(256 * 128 + 255) / 256, 256, 0, stream>>>(Wl0, Wlt0, 256, 128);
    k_transpose<<<(256 * 128 + 255) / 256, 256, 0, stream>>>(Wr0, Wrt0, 256, 128);
    k_transpose<<<(128 * 256 + 255) / 256, 256, 0, stream>>>(Wl1, Wlt1, 128, 256);
    k_transpose<<<(128 * 256 + 255) / 256, 256, 0, stream>>>(Wr1, Wrt1, 128, 256);

    // --- fused hops ---
    k_hop0<<<cN1 / 32, 256, 0, stream>>>(x, off0, srcs0, Wlt0, Wrt0, bl0, h);
    k_hop1<<<(cN2 + 31) / 32, 256, 0, stream>>>(h, off1, srcs1, Wlt1, Wrt1, bl1, out);
}

// Round 2
// 829.635 us; speedup vs baseline: 1.3241x; 1.3241x over previous
//
#include <hip/hip_runtime.h>
#include <hip/hip_bf16.h>

#define cN0 500000
#define cN1 100000
#define cN2 25000
#define cE0 1600000
#define cE1 400000

typedef __bf16 bf16x8 __attribute__((ext_vector_type(8)));
typedef __bf16 bf16x4 __attribute__((ext_vector_type(4)));
typedef float f32x4 __attribute__((ext_vector_type(4)));

// ---------------- CSR build ----------------

__global__ void k_hist(const int* __restrict__ dst, int E, int* __restrict__ cnt) {
    int i = blockIdx.x * blockDim.x + threadIdx.x;
    if (i < E) atomicAdd(&cnt[dst[i]], 1);
}

__global__ void k_scan1(int* __restrict__ a, int n, int* __restrict__ bsum) {
    __shared__ int lds[256];
    const int t = threadIdx.x;
    const int base = blockIdx.x * 1024 + t * 4;
    int v0 = (base + 0 < n) ? a[base + 0] : 0;
    int v1 = (base + 1 < n) ? a[base + 1] : 0;
    int v2 = (base + 2 < n) ? a[base + 2] : 0;
    int v3 = (base + 3 < n) ? a[base + 3] : 0;
    const int s = v0 + v1 + v2 + v3;
    lds[t] = s;
    __syncthreads();
    int x = s;
    for (int d = 1; d < 256; d <<= 1) {
        int y = (t >= d) ? lds[t - d] : 0;
        __syncthreads();
        x += y;
        lds[t] = x;
        __syncthreads();
    }
    if (t == 255) bsum[blockIdx.x] = x;
    int e0 = x - s;
    int e1 = e0 + v0, e2 = e1 + v1, e3 = e2 + v2;
    if (base + 0 < n) a[base + 0] = e0;
    if (base + 1 < n) a[base + 1] = e1;
    if (base + 2 < n) a[base + 2] = e2;
    if (base + 3 < n) a[base + 3] = e3;
}

__global__ void k_scan2(int* __restrict__ bsum, int nb) {
    __shared__ int lds[128];
    const int t = threadIdx.x;
    int v = (t < nb) ? bsum[t] : 0;
    lds[t] = v;
    __syncthreads();
    int x = v;
    for (int d = 1; d < 128; d <<= 1) {
        int y = (t >= d) ? lds[t - d] : 0;
        __syncthreads();
        x += y;
        lds[t] = x;
        __syncthreads();
    }
    if (t < nb) bsum[t] = x - v;
}

__global__ void k_scan3(int* __restrict__ a, int n, const int* __restrict__ bsum, int total) {
    int i = blockIdx.x * blockDim.x + threadIdx.x;
    if (i < n) a[i] += bsum[i >> 10];
    if (i == 0) a[n] = total;
}

__global__ void k_copy(int* __restrict__ dst, const int* __restrict__ src, int n) {
    int i = blockIdx.x * blockDim.x + threadIdx.x;
    if (i < n) dst[i] = src[i];
}

__global__ void k_scatter(const int* __restrict__ esrc, const int* __restrict__ edst, int E,
                          int* __restrict__ cur, int* __restrict__ srcs) {
    int i = blockIdx.x * blockDim.x + threadIdx.x;
    if (i < E) {
        int p = atomicAdd(&cur[edst[i]], 1);
        srcs[p] = esrc[i];
    }
}

// ---------------- weight concat (fp32 -> bf16) ----------------
// Wcat0 [256 x 256]: row j = [Wl0[j,:128] | Wr0[j,:128]]
__global__ void k_wcat0(const float* __restrict__ Wl, const float* __restrict__ Wr,
                        __bf16* __restrict__ Wc) {
    int i = blockIdx.x * blockDim.x + threadIdx.x;   // 256*256
    if (i < 256 * 256) {
        int j = i >> 8, k = i & 255;
        float v = (k < 128) ? Wl[j * 128 + k] : Wr[j * 128 + (k - 128)];
        Wc[i] = (__bf16)v;
    }
}
// Wcat1 [128 x 512]: row j = [Wl1[j,:256] | Wr1[j,:256]]
__global__ void k_wcat1(const float* __restrict__ Wl, const float* __restrict__ Wr,
                        __bf16* __restrict__ Wc) {
    int i = blockIdx.x * blockDim.x + threadIdx.x;   // 128*512
    if (i < 128 * 512) {
        int j = i >> 9, k = i & 511;
        float v = (k < 256) ? Wl[j * 256 + k] : Wr[j * 256 + (k - 256)];
        Wc[i] = (__bf16)v;
    }
}

// ---------------- hop0 aggregation: M0[g] = [bf16(mean x_src) | bf16(x[g])] ----------------
// half-wave (32 lanes) per node, lane = 4 fp32 dims (16B float4 loads)
__global__ __launch_bounds__(256) void k_agg0(
    const float* __restrict__ x,
    const int* __restrict__ off, const int* __restrict__ srcs,
    __bf16* __restrict__ M0)
{
    const int tid = threadIdx.x;
    const int slot = tid >> 5;          // 0..7
    const int ln = tid & 31;            // dims ln*4 .. ln*4+3
    const int g = blockIdx.x * 8 + slot;
    if (g >= cN1) return;
    const int e0 = off[g], e1 = off[g + 1];
    float ax = 0.f, ay = 0.f, az = 0.f, aw = 0.f;
    int e = e0;
    for (; e + 4 <= e1; e += 4) {
        const int s0 = srcs[e], s1 = srcs[e + 1], s2 = srcs[e + 2], s3 = srcs[e + 3];
        const float4 r0 = *(const float4*)(x + (size_t)s0 * 128 + ln * 4);
        const float4 r1 = *(const float4*)(x + (size_t)s1 * 128 + ln * 4);
        const float4 r2 = *(const float4*)(x + (size_t)s2 * 128 + ln * 4);
        const float4 r3 = *(const float4*)(x + (size_t)s3 * 128 + ln * 4);
        ax += (r0.x + r1.x) + (r2.x + r3.x);
        ay += (r0.y + r1.y) + (r2.y + r3.y);
        az += (r0.z + r1.z) + (r2.z + r3.z);
        aw += (r0.w + r1.w) + (r2.w + r3.w);
    }
    for (; e < e1; ++e) {
        const int s = srcs[e];
        const float4 r = *(const float4*)(x + (size_t)s * 128 + ln * 4);
        ax += r.x; ay += r.y; az += r.z; aw += r.w;
    }
    const int cnt = e1 - e0;
    const float inv = 1.f / (float)(cnt > 0 ? cnt : 1);
    bf16x4 oa;
    oa[0] = (__bf16)(ax * inv); oa[1] = (__bf16)(ay * inv);
    oa[2] = (__bf16)(az * inv); oa[3] = (__bf16)(aw * inv);
    *(bf16x4*)(M0 + (size_t)g * 256 + ln * 4) = oa;
    const float4 xd = *(const float4*)(x + (size_t)g * 128 + ln * 4);
    bf16x4 ox;
    ox[0] = (__bf16)xd.x; ox[1] = (__bf16)xd.y;
    ox[2] = (__bf16)xd.z; ox[3] = (__bf16)xd.w;
    *(bf16x4*)(M0 + (size_t)g * 256 + 128 + ln * 4) = ox;
}

// ---------------- hop1 aggregation: M1[g] = [bf16(mean h_src) | h[g]] ----------------
// full wave per node, lane = 4 bf16 dims of 256 (8B loads)
__global__ __launch_bounds__(256) void k_agg1(
    const __bf16* __restrict__ h,
    const int* __restrict__ off, const int* __restrict__ srcs,
    __bf16* __restrict__ M1)
{
    const int tid = threadIdx.x;
    const int wave = tid >> 6;
    const int lane = tid & 63;          // dims lane*4 .. +3
    const int g = blockIdx.x * 4 + wave;
    if (g >= cN2) return;
    const int e0 = off[g], e1 = off[g + 1];
    float a0 = 0.f, a1 = 0.f, a2 = 0.f, a3 = 0.f;
    int e = e0;
    for (; e + 4 <= e1; e += 4) {
        const int s0 = srcs[e], s1 = srcs[e + 1], s2 = srcs[e + 2], s3 = srcs[e + 3];
        const bf16x4 r0 = *(const bf16x4*)(h + (size_t)s0 * 256 + lane * 4);
        const bf16x4 r1 = *(const bf16x4*)(h + (size_t)s1 * 256 + lane * 4);
        const bf16x4 r2 = *(const bf16x4*)(h + (size_t)s2 * 256 + lane * 4);
        const bf16x4 r3 = *(const bf16x4*)(h + (size_t)s3 * 256 + lane * 4);
        a0 += (float)r0[0] + (float)r1[0] + (float)r2[0] + (float)r3[0];
        a1 += (float)r0[1] + (float)r1[1] + (float)r2[1] + (float)r3[1];
        a2 += (float)r0[2] + (float)r1[2] + (float)r2[2] + (float)r3[2];
        a3 += (float)r0[3] + (float)r1[3] + (float)r2[3] + (float)r3[3];
    }
    for (; e < e1; ++e) {
        const int s = srcs[e];
        const bf16x4 r = *(const bf16x4*)(h + (size_t)s * 256 + lane * 4);
        a0 += (float)r[0]; a1 += (float)r[1]; a2 += (float)r[2]; a3 += (float)r[3];
    }
    const int cnt = e1 - e0;
    const float inv = 1.f / (float)(cnt > 0 ? cnt : 1);
    bf16x4 oa;
    oa[0] = (__bf16)(a0 * inv); oa[1] = (__bf16)(a1 * inv);
    oa[2] = (__bf16)(a2 * inv); oa[3] = (__bf16)(a3 * inv);
    *(bf16x4*)(M1 + (size_t)g * 512 + lane * 4) = oa;
    *(bf16x4*)(M1 + (size_t)g * 512 + 256 + lane * 4) =
        *(const bf16x4*)(h + (size_t)g * 256 + lane * 4);
}

// ---------------- bf16 MFMA GEMM: C = act(Mm[Mrows x K] @ W[N x K]^T + bias) ----------------
// block = 4 waves, tile 128(M) x 128(N); wave = 64x64 via 4x4 of 16x16x32 MFMA.
// Fragments loaded directly from global (W is L2-resident; Mm streamed).
template<int K, int LDC, bool RELU, bool OUTBF16>
__global__ __launch_bounds__(256) void k_gemm(
    const __bf16* __restrict__ Mm, const __bf16* __restrict__ W,
    const float* __restrict__ bias,
    float* __restrict__ outf, __bf16* __restrict__ outb, int Mrows)
{
    const int tid = threadIdx.x;
    const int l = tid & 63;
    const int w = tid >> 6;
    const int wm = w & 1, wn = w >> 1;
    const int row0 = blockIdx.x * 128 + wm * 64;
    const int col0 = blockIdx.y * 128 + wn * 64;
    const int lr = l & 15;          // row (A) / col (B) within fragment
    const int lk = (l >> 4) * 8;    // k offset within fragment

    const __bf16* pa[4];
    const __bf16* pb[4];
    #pragma unroll
    for (int i = 0; i < 4; ++i) {
        int r = row0 + i * 16 + lr;
        r = (r < Mrows) ? r : (Mrows - 1);
        pa[i] = Mm + (size_t)r * K + lk;
        pb[i] = W + (size_t)(col0 + i * 16 + lr) * K + lk;
    }
    f32x4 acc[4][4];
    #pragma unroll
    for (int i = 0; i < 4; ++i)
        #pragma unroll
        for (int j = 0; j < 4; ++j)
            acc[i][j] = (f32x4)0.0f;

    #pragma unroll 2
    for (int k0 = 0; k0 < K; k0 += 32) {
        bf16x8 fa[4], fb[4];
        #pragma unroll
        for (int i = 0; i < 4; ++i) fa[i] = *(const bf16x8*)(pa[i] + k0);
        #pragma unroll
        for (int j = 0; j < 4; ++j) fb[j] = *(const bf16x8*)(pb[j] + k0);
        #pragma unroll
        for (int i = 0; i < 4; ++i)
            #pragma unroll
            for (int j = 0; j < 4; ++j)
                acc[i][j] = __builtin_amdgcn_mfma_f32_16x16x32_bf16(fa[i], fb[j], acc[i][j], 0, 0, 0);
    }

    // C/D layout: col = lane&15, row = (lane>>4)*4 + reg  [m89/m91-verified]
    #pragma unroll
    for (int j = 0; j < 4; ++j) {
        const int colg = col0 + j * 16 + lr;
        const float bj = bias[colg];
        #pragma unroll
        for (int i = 0; i < 4; ++i) {
            #pragma unroll
            for (int reg = 0; reg < 4; ++reg) {
                const int rowg = row0 + i * 16 + (l >> 4) * 4 + reg;
                if (rowg < Mrows) {
                    float v = acc[i][j][reg] + bj;
                    if (RELU) v = fmaxf(v, 0.f);
                    if (OUTBF16) outb[(size_t)rowg * LDC + colg] = (__bf16)v;
                    else         outf[(size_t)rowg * LDC + colg] = v;
                }
            }
        }
    }
}

// ---------------- launch ----------------

extern "C" void kernel_launch(void* const* d_in, const int* in_sizes, int n_in,
                              void* d_out, int out_size, void* d_ws, size_t ws_size,
                              hipStream_t stream) {
    const float* x   = (const float*)d_in[0];
    const float* Wl0 = (const float*)d_in[1];
    const float* bl0 = (const float*)d_in[2];
    const float* Wr0 = (const float*)d_in[3];
    const float* Wl1 = (const float*)d_in[4];
    const float* bl1 = (const float*)d_in[5];
    const float* Wr1 = (const float*)d_in[6];
    const int* e0s = (const int*)d_in[7];
    const int* e0d = (const int*)d_in[8];
    const int* e1s = (const int*)d_in[9];
    const int* e1d = (const int*)d_in[10];
    float* out = (float*)d_out;

    char* ws = (char*)d_ws;
    size_t pos = 0;
    auto alloc = [&](size_t nb) -> void* {
        void* p = ws + pos;
        pos += (nb + 255) & ~(size_t)255;
        return p;
    };
    // M0 [100K x 256] bf16 (51.2MB); M1 [25K x 512] bf16 (25.6MB) aliases M0 (M0 dead after gemm1)
    __bf16* M0   = (__bf16*)alloc((size_t)cN1 * 256 * 2);
    __bf16* M1   = M0;
    __bf16* h    = (__bf16*)alloc((size_t)cN1 * 256 * 2);   // 51.2MB
    int* off0    = (int*)alloc((size_t)(cN1 + 1) * 4);
    int* cur0    = (int*)alloc((size_t)cN1 * 4);
    int* srcs0   = (int*)alloc((size_t)cE0 * 4);
    int* off1    = (int*)alloc((size_t)(cN2 + 1) * 4);
    int* cur1    = (int*)alloc((size_t)cN2 * 4);
    int* srcs1   = (int*)alloc((size_t)cE1 * 4);
    int* bsum    = (int*)alloc(128 * 4);
    __bf16* Wc0  = (__bf16*)alloc(256 * 256 * 2);
    __bf16* Wc1  = (__bf16*)alloc(128 * 512 * 2);
    (void)ws_size; (void)in_sizes; (void)n_in; (void)out_size;

    // --- CSR build ---
    hipMemsetAsync(off0, 0, (size_t)(cN1 + 1) * 4, stream);
    hipMemsetAsync(off1, 0, (size_t)(cN2 + 1) * 4, stream);
    k_hist<<<(cE0 + 255) / 256, 256, 0, stream>>>(e0d, cE0, off0);
    k_hist<<<(cE1 + 255) / 256, 256, 0, stream>>>(e1d, cE1, off1);

    const int nb0 = (cN1 + 1023) / 1024;
    k_scan1<<<nb0, 256, 0, stream>>>(off0, cN1, bsum);
    k_scan2<<<1, 128, 0, stream>>>(bsum, nb0);
    k_scan3<<<(cN1 + 255) / 256, 256, 0, stream>>>(off0, cN1, bsum, cE0);
    k_copy<<<(cN1 + 255) / 256, 256, 0, stream>>>(cur0, off0, cN1);
    k_scatter<<<(cE0 + 255) / 256, 256, 0, stream>>>(e0s, e0d, cE0, cur0, srcs0);

    const int nb1 = (cN2 + 1023) / 1024;
    k_scan1<<<nb1, 256, 0, stream>>>(off1, cN2, bsum);
    k_scan2<<<1, 128, 0, stream>>>(bsum, nb1);
    k_scan3<<<(cN2 + 255) / 256, 256, 0, stream>>>(off1, cN2, bsum, cE1);
    k_copy<<<(cN2 + 255) / 256, 256, 0, stream>>>(cur1, off1, cN2);
    k_scatter<<<(cE1 + 255) / 256, 256, 0, stream>>>(e1s, e1d, cE1, cur1, srcs1);

    // --- weights to bf16 concat ---
    k_wcat0<<<(256 * 256 + 255) / 256, 256, 0, stream>>>(Wl0, Wr0, Wc0);
    k_wcat1<<<(128 * 512 + 255) / 256, 256, 0, stream>>>(Wl1, Wr1, Wc1);

    // --- hop 0 ---
    k_agg0<<<(cN1 + 7) / 8, 256, 0, stream>>>(x, off0, srcs0, M0);
    {
        dim3 grid((cN1 + 127) / 128, 2);
        k_gemm<256, 256, true, true><<<grid, 256, 0, stream>>>(M0, Wc0, bl0, nullptr, h, cN1);
    }
    // --- hop 1 ---
    k_agg1<<<(cN2 + 3) / 4, 256, 0, stream>>>(h, off1, srcs1, M1);
    {
        dim3 grid((cN2 + 127) / 128, 1);
        k_gemm<512, 128, false, false><<<grid, 256, 0, stream>>>(M1, Wc1, bl1, out, nullptr, cN2);
    }
}